// Round 8
// baseline (313.666 us; speedup 1.0000x reference)
//
#include <hip/hip_runtime.h>
#include <math.h>

constexpr int Bn  = 2;
constexpr int Cn  = 128;
constexpr int Hn  = 96;
constexpr int Wn  = 96;
constexpr int HWn = Hn * Wn;        // 9216
constexpr int CHWn = Cn * HWn;      // 1179648
constexpr int KCn = Cn * 9;         // 1152
constexpr float EPSn = 1e-5f;
constexpr int PX   = 32;            // pixels per block
constexpr int SROW = 136;           // S row stride in shorts (272B, 16B-aligned)

typedef short bf16x8 __attribute__((ext_vector_type(8)));
typedef float f32x4  __attribute__((ext_vector_type(4)));

static __device__ inline short f2bf(float f) {
    union { float f; unsigned u; } v; v.f = f;
    unsigned r = v.u + 0x7fff + ((v.u >> 16) & 1);
    return (short)(r >> 16);
}
static __device__ inline unsigned pack2(float a, float b) {
    return (unsigned)(unsigned short)f2bf(a) | ((unsigned)(unsigned short)f2bf(b) << 16);
}

// k-major permuted weights: wb[o][k*128 + c] = w[o][c*9 + k]
__global__ __launch_bounds__(256) void cvt_w_kernel(
    const float* __restrict__ w, short* __restrict__ wb)
{
    int t = blockIdx.x * 256 + threadIdx.x;   // 128*1152
    if (t >= Cn * KCn) return;
    int o = t / KCn, r = t % KCn;
    int k = r >> 7, c = r & 127;
    wb[t] = f2bf(w[o * KCn + c * 9 + k]);
}

__global__ __launch_bounds__(256) void cvt_ow_kernel(
    const float* __restrict__ ow, short* __restrict__ owb)
{
    int t = blockIdx.x * 256 + threadIdx.x;   // 32*1152
    if (t >= 32 * KCn) return;
    int row = t / KCn, r = t % KCn;
    int k = r >> 7, c = r & 127;
    owb[t] = (row < 27) ? f2bf(ow[row * KCn + c * 9 + k]) : (short)0;
}

// NCHW -> NHWC (global-pixel-major): xT[(b*HWn+sp)*128 + c] = x[b][c][sp]
__global__ __launch_bounds__(256) void nchw2nhwc(
    const float* __restrict__ x, float* __restrict__ xT)
{
    __shared__ float Tl[128][65];
    const int t = threadIdx.x;
    const int pix0 = blockIdx.x * 64;
    const int b   = pix0 / HWn;
    const int sp0 = pix0 - b * HWn;
    const float* xb = x + b * CHWn + sp0 + (t & 63);
    const int c0 = t >> 6;
#pragma unroll 8
    for (int i = 0; i < 32; ++i) {
        const int c = c0 + 4 * i;
        Tl[c][t & 63] = xb[c * HWn];
    }
    __syncthreads();
    float* dst = xT + pix0 * 128;
#pragma unroll 8
    for (int i = 0; i < 32; ++i) {
        const int o = t + 256 * i;
        dst[o] = Tl[o & 127][o >> 7];
    }
}

// One fused residual block: 32 pixels / 512 threads, tap-tiled LDS, NHWC.
__global__ __launch_bounds__(512, 8) void fused_stage(
    const float* __restrict__ xT, const short* __restrict__ wb,
    const short* __restrict__ owb, const float* __restrict__ obv,
    const float* __restrict__ gv, const float* __restrict__ bv,
    const float* __restrict__ mv, const float* __restrict__ vv,
    float* __restrict__ outT, float* __restrict__ outC, int dil, int last)
{
    __shared__ short S[PX * SROW];            // 8704B tap tile S[px][c]
    __shared__ float offL[PX][18];
    __shared__ float maskL[PX][9];
    __shared__ float prmF[PX * 9][4];
    __shared__ int   prmI[PX * 9][4];

    const int t  = threadIdx.x;
    const int l  = t & 63;
    const int wv = t >> 6;                    // wave 0..7
    const int lr = l & 15;                    // fragment row/col lane
    const int lq = l >> 4;                    // fragment quad 0..3

    // XCD-aware bijective swizzle: 576 blocks = 8 XCDs x 72 contiguous
    const int bid = blockIdx.x;
    const int swz = (bid & 7) * 72 + (bid >> 3);
    const int pix0 = swz * PX;                // 96%32==0: never crosses a row
    const int b   = pix0 / HWn;
    const int sp0 = pix0 - b * HWn;
    const int hy  = sp0 / Wn;
    const int wx0 = sp0 - hy * Wn;
    const int basep = b * HWn;

    // ---------------- pass 1: int gather + offconv, tap-by-tap ----------
    const int mh = wv & 1, pf1 = (wv >> 1) & 1, kh = wv >> 2;
    f32x4 oacc = {0.f, 0.f, 0.f, 0.f};
    for (int k = 0; k < 9; ++k) {
        const int iy = hy + (k / 3 - 1) * dil;
        const int kx = (k % 3 - 1) * dil;
        const bool yv = (iy >= 0) && (iy < Hn);
#pragma unroll
        for (int i = 0; i < 4; ++i) {
            const int pp = wv * 4 + i;
            const int ix = wx0 + pp + kx;
            const bool v = yv && (ix >= 0) && (ix < Wn);
            const int aof = v ? (basep + iy * Wn + ix) : basep;
            const float mkf = v ? 1.f : 0.f;
            float2 val = ((const float2*)(xT + aof * 128))[l];
            ((unsigned*)&S[pp * SROW])[l] = pack2(val.x * mkf, val.y * mkf);
        }
        __syncthreads();
        {   // offconv MFMA: wave = (M-half, px-frag, K-half); K=64 -> 2 steps
            const short* arow = owb + (mh * 16 + lr) * KCn + k * 128 + kh * 64 + lq * 8;
            const short* brow = &S[(pf1 * 16 + lr) * SROW + kh * 64 + lq * 8];
#pragma unroll
            for (int s2 = 0; s2 < 2; ++s2) {
                bf16x8 af = *(const bf16x8*)(arow + s2 * 32);
                bf16x8 bf = *(const bf16x8*)(brow + s2 * 32);
                oacc = __builtin_amdgcn_mfma_f32_16x16x32_bf16(af, bf, oacc, 0, 0, 0);
            }
        }
        __syncthreads();
    }
    // reduce the two K-halves (waves wv and wv+4 share (mh,pf1))
    float* red = (float*)S;                   // alias S (8KB <= 8.7KB)
    *(f32x4*)&red[wv * 256 + l * 4] = oacc;
    __syncthreads();
    if (wv < 4) {
        f32x4 a = *(const f32x4*)&red[wv * 256 + l * 4];
        f32x4 c = *(const f32x4*)&red[(wv + 4) * 256 + l * 4];
        f32x4 sm = a + c;
        const int px = (wv >> 1) * 16 + lr;
#pragma unroll
        for (int r = 0; r < 4; ++r) {
            int oc = (wv & 1) * 16 + lq * 4 + r;
            if (oc < 18) {
                offL[px][oc] = sm[r] + obv[oc];
            } else if (oc < 27) {
                float z = sm[r] + obv[oc];
                maskL[px][oc - 18] = 1.f / (1.f + expf(-z));
            }
        }
    }
    __syncthreads();

    // ---- bilinear param phase: one (p,k) per thread, 288 threads ----
    if (t < 288) {
        const int p = t / 9, k = t - 9 * (t / 9);
        const float offy = offL[p][2 * k];
        const float offx = offL[p][2 * k + 1];
        const float m    = maskL[p][k];
        const float py = (float)(hy + (k / 3 - 1) * dil) + offy;
        const float px = (float)(wx0 + p + (k % 3 - 1) * dil) + offx;
        const float y0f = floorf(py), x0f = floorf(px);
        const float ly = py - y0f, lx = px - x0f;
        const int y0 = (int)y0f, x0 = (int)x0f;
        const float yv0 = (y0 >= 0 && y0 < Hn)      ? 1.f : 0.f;
        const float yv1 = (y0 >= -1 && y0 < Hn - 1) ? 1.f : 0.f;
        const float xv0 = (x0 >= 0 && x0 < Wn)      ? 1.f : 0.f;
        const float xv1 = (x0 >= -1 && x0 < Wn - 1) ? 1.f : 0.f;
        const float wy0 = (1.f - ly) * yv0 * m;
        const float wy1 = ly * yv1 * m;
        const float wxa = (1.f - lx) * xv0;
        const float wxb = lx * xv1;
        prmF[t][0] = wy0 * wxa;  prmF[t][1] = wy0 * wxb;
        prmF[t][2] = wy1 * wxa;  prmF[t][3] = wy1 * wxb;
        const int y0c = min(max(y0, 0), Hn - 1), y1c = min(max(y0 + 1, 0), Hn - 1);
        const int x0c = min(max(x0, 0), Wn - 1), x1c = min(max(x0 + 1, 0), Wn - 1);
        prmI[t][0] = (basep + y0c * Wn + x0c) * 128;
        prmI[t][1] = (basep + y1c * Wn + x1c) * 128;
        prmI[t][2] = (x1c - x0c) * 128;
        prmI[t][3] = 0;
    }
    __syncthreads();

    // ---------------- pass 2: bilinear gather + dconv, tap-by-tap -------
    const int ocg = wv >> 1, pf = wv & 1;     // 4 oc-groups x 2 px-groups
    f32x4 dacc0 = {0.f, 0.f, 0.f, 0.f}, dacc1 = {0.f, 0.f, 0.f, 0.f};
    for (int k = 0; k < 9; ++k) {
#pragma unroll 2
        for (int i = 0; i < 4; ++i) {
            const int pp = wv * 4 + i;
            const int id = pp * 9 + k;
            const f32x4 pfv = *(const f32x4*)&prmF[id][0];
            const int4  piv = *(const int4*)&prmI[id][0];
            const float* xp = xT + piv.x;
            const float* xq = xT + piv.y;
            float2 v00 = ((const float2*)xp)[l];
            float2 v01 = ((const float2*)(xp + piv.z))[l];
            float2 v10 = ((const float2*)(xq - piv.z))[l];
            float2 v11 = ((const float2*)xq)[l];
            float s0 = pfv[0] * v00.x + pfv[1] * v01.x + pfv[2] * v10.x + pfv[3] * v11.x;
            float s1 = pfv[0] * v00.y + pfv[1] * v01.y + pfv[2] * v10.y + pfv[3] * v11.y;
            ((unsigned*)&S[pp * SROW])[l] = pack2(s0, s1);
        }
        __syncthreads();
        {   // dconv MFMA: 4 K-steps, B-frag shared across 2 M-frags
            const short* brow = &S[(pf * 16 + lr) * SROW + lq * 8];
            const short* arow = wb + (ocg * 32 + lr) * KCn + k * 128 + lq * 8;
#pragma unroll
            for (int s = 0; s < 4; ++s) {
                bf16x8 bf = *(const bf16x8*)(brow + s * 32);
                bf16x8 a0 = *(const bf16x8*)(arow + s * 32);
                bf16x8 a1 = *(const bf16x8*)(arow + 16 * KCn + s * 32);
                dacc0 = __builtin_amdgcn_mfma_f32_16x16x32_bf16(a0, bf, dacc0, 0, 0, 0);
                dacc1 = __builtin_amdgcn_mfma_f32_16x16x32_bf16(a1, bf, dacc1, 0, 0, 0);
            }
        }
        __syncthreads();
    }

    // ---------------- epilogue: BN + ReLU + residual --------------------
    if (last) {
        const int px = pf * 16 + lr;
#pragma unroll
        for (int mf = 0; mf < 2; ++mf) {
            const f32x4 dv = mf ? dacc1 : dacc0;
#pragma unroll
            for (int r = 0; r < 4; ++r) {
                const int oc = ocg * 32 + mf * 16 + lq * 4 + r;
                const float sc = gv[oc] * rsqrtf(vv[oc] + EPSn);
                float y = (dv[r] - mv[oc]) * sc + bv[oc];
                y = fmaxf(y, 0.f) + xT[(pix0 + px) * 128 + oc];
                outC[b * CHWn + oc * HWn + sp0 + px] = y;
            }
        }
    } else {
        float* O = (float*)S;                 // O[16][132] per px-half
#pragma unroll
        for (int h = 0; h < 2; ++h) {
            __syncthreads();
            if (pf == h) {
#pragma unroll
                for (int mf = 0; mf < 2; ++mf) {
                    const f32x4 dv = mf ? dacc1 : dacc0;
                    const int oc0 = ocg * 32 + mf * 16 + lq * 4;
                    f32x4 y;
#pragma unroll
                    for (int r = 0; r < 4; ++r) {
                        const int oc = oc0 + r;
                        const float sc = gv[oc] * rsqrtf(vv[oc] + EPSn);
                        y[r] = fmaxf((dv[r] - mv[oc]) * sc + bv[oc], 0.f);
                    }
                    *(f32x4*)&O[lr * 132 + oc0] = y;
                }
            }
            __syncthreads();
            const int o = t * 4;
            const int qp = o >> 7, qc = o & 127;
            const int gpx = pix0 + h * 16 + qp;
            f32x4 yv = *(f32x4*)&O[qp * 132 + qc];
            f32x4 rv = *(const f32x4*)&xT[gpx * 128 + qc];
            yv += rv;
            *(f32x4*)&outT[gpx * 128 + qc] = yv;
        }
    }
}

extern "C" void kernel_launch(void* const* d_in, const int* in_sizes, int n_in,
                              void* d_out, int out_size, void* d_ws, size_t ws_size,
                              hipStream_t stream) {
    (void)in_sizes; (void)n_in; (void)out_size; (void)ws_size;

    const float* hu = (const float*)d_in[0];

    short* wb  = (short*)d_ws;                    // 3 * 147456 shorts
    short* owb = wb + 3 * Cn * KCn;               // 3 * 36864 shorts
    float* T0  = (float*)(owb + 3 * 32 * KCn);    // Bn*CHWn floats (NHWC)
    float* T1  = T0 + Bn * CHWn;                  // Bn*CHWn floats (NHWC)

    for (int i = 0; i < 3; ++i) {
        cvt_w_kernel<<<(Cn * KCn + 255) / 256, 256, 0, stream>>>(
            (const float*)d_in[3 + 7 * i], wb + i * Cn * KCn);
        cvt_ow_kernel<<<(32 * KCn + 255) / 256, 256, 0, stream>>>(
            (const float*)d_in[1 + 7 * i], owb + i * 32 * KCn);
    }

    nchw2nhwc<<<(Bn * HWn) / 64, 256, 0, stream>>>(hu, T0);

    const int dils[3] = {2, 4, 8};
    const float* ins[3] = {T0, T1, T0};
    float*       outsT[3] = {T1, T0, nullptr};
    const int nblk = (Bn * HWn) / PX;             // 576

    for (int i = 0; i < 3; ++i) {
        const float* obv = (const float*)d_in[2 + 7 * i];
        const float* gv  = (const float*)d_in[4 + 7 * i];
        const float* bv  = (const float*)d_in[5 + 7 * i];
        const float* mv  = (const float*)d_in[6 + 7 * i];
        const float* vv  = (const float*)d_in[7 + 7 * i];
        const int last = (i == 2);

        fused_stage<<<nblk, 512, 0, stream>>>(
            ins[i], wb + i * Cn * KCn, owb + i * 32 * KCn, obv,
            gv, bv, mv, vv, outsT[i], last ? (float*)d_out : nullptr,
            dils[i], last);
    }
}

// Round 9
// 267.518 us; speedup vs baseline: 1.1725x; 1.1725x over previous
//
#include <hip/hip_runtime.h>
#include <math.h>

constexpr int Bn  = 2;
constexpr int Cn  = 128;
constexpr int Hn  = 96;
constexpr int Wn  = 96;
constexpr int HWn = Hn * Wn;        // 9216
constexpr int CHWn = Cn * HWn;      // 1179648
constexpr int KCn = Cn * 9;         // 1152
constexpr float EPSn = 1e-5f;
constexpr int KPAD = 1160;          // LDS row stride in shorts (2320B, 16B-aligned)

typedef short bf16x8 __attribute__((ext_vector_type(8)));
typedef float f32x4  __attribute__((ext_vector_type(4)));

static __device__ inline short f2bf(float f) {
    union { float f; unsigned u; } v; v.f = f;
    unsigned r = v.u + 0x7fff + ((v.u >> 16) & 1);
    return (short)(r >> 16);
}
static __device__ inline unsigned pack2(float a, float b) {
    return (unsigned)(unsigned short)f2bf(a) | ((unsigned)(unsigned short)f2bf(b) << 16);
}

// k-major permuted weights: wb[o][k*128 + c] = w[o][c*9 + k]
__global__ __launch_bounds__(256) void cvt_w_kernel(
    const float* __restrict__ w, short* __restrict__ wb)
{
    int t = blockIdx.x * 256 + threadIdx.x;   // 128*1152
    if (t >= Cn * KCn) return;
    int o = t / KCn, r = t % KCn;
    int k = r >> 7, c = r & 127;
    wb[t] = f2bf(w[o * KCn + c * 9 + k]);
}

__global__ __launch_bounds__(256) void cvt_ow_kernel(
    const float* __restrict__ ow, short* __restrict__ owb)
{
    int t = blockIdx.x * 256 + threadIdx.x;   // 32*1152
    if (t >= 32 * KCn) return;
    int row = t / KCn, r = t % KCn;
    int k = r >> 7, c = r & 127;
    owb[t] = (row < 27) ? f2bf(ow[row * KCn + c * 9 + k]) : (short)0;
}

// NCHW -> NHWC (global-pixel-major): xT[(b*HWn+sp)*128 + c] = x[b][c][sp]
__global__ __launch_bounds__(256) void nchw2nhwc(
    const float* __restrict__ x, float* __restrict__ xT)
{
    __shared__ float Tl[128][65];
    const int t = threadIdx.x;
    const int pix0 = blockIdx.x * 64;         // 64 pixels, never crosses batch
    const int b   = pix0 / HWn;
    const int sp0 = pix0 - b * HWn;
    const float* xb = x + b * CHWn + sp0 + (t & 63);
    const int c0 = t >> 6;                    // 0..3
#pragma unroll 8
    for (int i = 0; i < 32; ++i) {
        const int c = c0 + 4 * i;
        Tl[c][t & 63] = xb[c * HWn];
    }
    __syncthreads();
    float* dst = xT + pix0 * 128;
#pragma unroll 8
    for (int i = 0; i < 32; ++i) {
        const int o = t + 256 * i;            // 0..8191
        dst[o] = Tl[o & 127][o >> 7];
    }
}

// One fused residual block, 16 pixels / 512 threads, NHWC input, k-major K.
// Bilinear params: lanes 0..17 of each wave compute the wave's 18 (pixel,tap)
// sets; gather-bil broadcasts them via v_readlane (wave-uniform -> SGPR base).
__global__ __launch_bounds__(512, 8) void fused_stage(
    const float* __restrict__ xT, const short* __restrict__ wb,
    const short* __restrict__ owb, const float* __restrict__ obv,
    const float* __restrict__ gv, const float* __restrict__ bv,
    const float* __restrict__ mv, const float* __restrict__ vv,
    float* __restrict__ outT, float* __restrict__ outC, int dil, int last)
{
    __shared__ short S[16 * KPAD];            // im2col tile S[p][K'], 37120B
    __shared__ float offL[16][18];
    __shared__ float maskL[16][9];

    const int t   = threadIdx.x;
    const int l   = t & 63;
    const int wv  = t >> 6;                   // wave 0..7

    // XCD-aware bijective swizzle: 1152 blocks = 8 XCDs x 144 contiguous
    const int bid = blockIdx.x;
    const int swz = (bid & 7) * 144 + (bid >> 3);
    const int pix0 = swz * 16;                // never crosses a row (96%16==0)
    const int b   = pix0 / HWn;
    const int sp0 = pix0 - b * HWn;
    const int hy  = sp0 / Wn;
    const int wx0 = sp0 - hy * Wn;
    const int basep = b * HWn;

    // ---- gather-int (NHWC): wave = (pixel,tap) pair, lane = channel pair ----
#pragma unroll 6
    for (int i = 0; i < 18; ++i) {
        const int di = i / 9;                 // 0/1
        const int k  = i - di * 9;
        const int pp = wv * 2 + di;
        const int iy = hy + (k / 3 - 1) * dil;
        const int ix = wx0 + pp + (k % 3 - 1) * dil;
        const bool v = (iy >= 0) && (iy < Hn) && (ix >= 0) && (ix < Wn);
        const int aof = v ? (basep + iy * Wn + ix) : basep;
        const float mkf = v ? 1.f : 0.f;
        float2 val = ((const float2*)(xT + aof * 128))[l];
        ((unsigned*)&S[pp * KPAD + k * 128])[l] = pack2(val.x * mkf, val.y * mkf);
    }
    __syncthreads();

    // ---- offconv GEMM: M=32 -> 2 M-halves x 4 K-sections over 8 waves ----
    const int mh = wv & 1, ks = wv >> 1;
    f32x4 oacc = {0.f, 0.f, 0.f, 0.f};
    {
        const short* oarow = owb + (mh * 16 + (l & 15)) * KCn + ks * 288 + ((l >> 4) * 8);
        const short* srow  = &S[(l & 15) * KPAD + ks * 288 + ((l >> 4) * 8)];
#pragma unroll 3
        for (int kk = 0; kk < 9; ++kk) {
            bf16x8 af = *(const bf16x8*)(oarow + kk * 32);
            bf16x8 bf = *(const bf16x8*)(srow + kk * 32);
            oacc = __builtin_amdgcn_mfma_f32_16x16x32_bf16(af, bf, oacc, 0, 0, 0);
        }
    }
    __syncthreads();                           // S(int) reads done
    float* red = (float*)S;                    // 8 waves x 64 lanes x f32x4 = 8KB
    *(f32x4*)&red[wv * 256 + l * 4] = oacc;
    __syncthreads();
    if (wv < 2) {
        f32x4 s0 = *(const f32x4*)&red[(0 * 2 + wv) * 256 + l * 4];
        f32x4 s1 = *(const f32x4*)&red[(1 * 2 + wv) * 256 + l * 4];
        f32x4 s2 = *(const f32x4*)&red[(2 * 2 + wv) * 256 + l * 4];
        f32x4 s3 = *(const f32x4*)&red[(3 * 2 + wv) * 256 + l * 4];
        f32x4 sm = (s0 + s1) + (s2 + s3);
#pragma unroll
        for (int r = 0; r < 4; ++r) {
            int oc = wv * 16 + ((l >> 4) << 2) + r;
            if (oc < 18) {
                offL[l & 15][oc] = sm[r] + obv[oc];
            } else if (oc < 27) {
                float z = sm[r] + obv[oc];
                maskL[l & 15][oc - 18] = 1.f / (1.f + expf(-z));
            }
        }
    }
    __syncthreads();                           // offL/maskL ready

    // ---- bilinear params: lane j (<18) computes set (pp=wv*2+j/9, k=j%9) ----
    int pw0i = 0, pw1i = 0, pw2i = 0, pw3i = 0, pa0 = 0, pa1 = 0, pdx = 0;
    if (l < 18) {
        const int p = wv * 2 + l / 9;
        const int k = l - 9 * (l / 9);
        const float offy = offL[p][2 * k];
        const float offx = offL[p][2 * k + 1];
        const float m    = maskL[p][k];
        const float py = (float)(hy + (k / 3 - 1) * dil) + offy;
        const float px = (float)(wx0 + p + (k % 3 - 1) * dil) + offx;
        const float y0f = floorf(py), x0f = floorf(px);
        const float ly = py - y0f, lx = px - x0f;
        const int y0 = (int)y0f, x0 = (int)x0f;
        const float yv0 = (y0 >= 0 && y0 < Hn)      ? 1.f : 0.f;
        const float yv1 = (y0 >= -1 && y0 < Hn - 1) ? 1.f : 0.f;
        const float xv0 = (x0 >= 0 && x0 < Wn)      ? 1.f : 0.f;
        const float xv1 = (x0 >= -1 && x0 < Wn - 1) ? 1.f : 0.f;
        const float wy0 = (1.f - ly) * yv0 * m;
        const float wy1 = ly * yv1 * m;
        const float wxa = (1.f - lx) * xv0;
        const float wxb = lx * xv1;
        pw0i = __float_as_int(wy0 * wxa);
        pw1i = __float_as_int(wy0 * wxb);
        pw2i = __float_as_int(wy1 * wxa);
        pw3i = __float_as_int(wy1 * wxb);
        const int y0c = min(max(y0, 0), Hn - 1), y1c = min(max(y0 + 1, 0), Hn - 1);
        const int x0c = min(max(x0, 0), Wn - 1), x1c = min(max(x0 + 1, 0), Wn - 1);
        pa0 = (basep + y0c * Wn + x0c) * 128;
        pa1 = (basep + y1c * Wn + x1c) * 128;
        pdx = (x1c - x0c) * 128;
    }
    // no barrier: params are wave-internal

    // ---- gather-bil (NHWC): params broadcast via readlane, lane = ch pair ----
#pragma unroll 3
    for (int i = 0; i < 18; ++i) {
        const int di = i / 9;
        const int k  = i - di * 9;
        const int pp = wv * 2 + di;
        const float w00 = __int_as_float(__builtin_amdgcn_readlane(pw0i, i));
        const float w01 = __int_as_float(__builtin_amdgcn_readlane(pw1i, i));
        const float w10 = __int_as_float(__builtin_amdgcn_readlane(pw2i, i));
        const float w11 = __int_as_float(__builtin_amdgcn_readlane(pw3i, i));
        const int a00 = __builtin_amdgcn_readlane(pa0, i);
        const int a11 = __builtin_amdgcn_readlane(pa1, i);
        const int dxk = __builtin_amdgcn_readlane(pdx, i);
        const float* xp = xT + a00;
        const float* xq = xT + a11;
        float2 v00 = ((const float2*)xp)[l];
        float2 v01 = ((const float2*)(xp + dxk))[l];
        float2 v10 = ((const float2*)(xq - dxk))[l];
        float2 v11 = ((const float2*)xq)[l];
        float s0 = w00 * v00.x + w01 * v01.x + w10 * v10.x + w11 * v11.x;
        float s1 = w00 * v00.y + w01 * v01.y + w10 * v10.y + w11 * v11.y;
        ((unsigned*)&S[pp * KPAD + k * 128])[l] = pack2(s0, s1);
    }
    __syncthreads();

    // ---- dconv GEMM: wave wv -> output channels wv*16 .. wv*16+15 ----
    f32x4 dacc = {0.f, 0.f, 0.f, 0.f};
    {
        const short* darow = wb + (wv * 16 + (l & 15)) * KCn + ((l >> 4) * 8);
        const short* srow  = &S[(l & 15) * KPAD + ((l >> 4) * 8)];
#pragma unroll 4
        for (int kk = 0; kk < 36; ++kk) {
            bf16x8 af = *(const bf16x8*)(darow + kk * 32);
            bf16x8 bf = *(const bf16x8*)(srow + kk * 32);
            dacc = __builtin_amdgcn_mfma_f32_16x16x32_bf16(af, bf, dacc, 0, 0, 0);
        }
    }

    // ---- epilogue: BN + ReLU + residual ----
    const int pp  = l & 15;
    const int ocb = wv * 16 + ((l >> 4) << 2);
    if (last) {
        // NCHW out, residual from NHWC input
#pragma unroll
        for (int r = 0; r < 4; ++r) {
            const int oc = ocb + r;
            const float sc = gv[oc] * rsqrtf(vv[oc] + EPSn);
            float y = (dacc[r] - mv[oc]) * sc + bv[oc];
            y = fmaxf(y, 0.f);
            y += xT[(pix0 + pp) * 128 + oc];
            outC[b * CHWn + oc * HWn + sp0 + pp] = y;
        }
    } else {
        __syncthreads();                       // all S reads done; alias O on S
        float* O = (float*)S;                  // O[16][132]
#pragma unroll
        for (int r = 0; r < 4; ++r) {
            const int oc = ocb + r;
            const float sc = gv[oc] * rsqrtf(vv[oc] + EPSn);
            float y = (dacc[r] - mv[oc]) * sc + bv[oc];
            O[pp * 132 + oc] = fmaxf(y, 0.f);
        }
        __syncthreads();
        // coalesced NHWC write + coalesced residual read
        const int o  = t * 4;                  // 0..2047
        const int qp = o >> 7, qc = o & 127;
        f32x4 yv = *(f32x4*)&O[qp * 132 + qc];
        f32x4 rv = *(const f32x4*)&xT[(pix0 + qp) * 128 + qc];
        yv += rv;
        *(f32x4*)&outT[(pix0 + qp) * 128 + qc] = yv;
    }
}

extern "C" void kernel_launch(void* const* d_in, const int* in_sizes, int n_in,
                              void* d_out, int out_size, void* d_ws, size_t ws_size,
                              hipStream_t stream) {
    (void)in_sizes; (void)n_in; (void)out_size; (void)ws_size;

    const float* hu = (const float*)d_in[0];

    short* wb  = (short*)d_ws;                    // 3 * 147456 shorts
    short* owb = wb + 3 * Cn * KCn;               // 3 * 36864 shorts
    float* T0  = (float*)(owb + 3 * 32 * KCn);    // Bn*CHWn floats (NHWC)
    float* T1  = T0 + Bn * CHWn;                  // Bn*CHWn floats (NHWC)

    for (int i = 0; i < 3; ++i) {
        cvt_w_kernel<<<(Cn * KCn + 255) / 256, 256, 0, stream>>>(
            (const float*)d_in[3 + 7 * i], wb + i * Cn * KCn);
        cvt_ow_kernel<<<(32 * KCn + 255) / 256, 256, 0, stream>>>(
            (const float*)d_in[1 + 7 * i], owb + i * 32 * KCn);
    }

    nchw2nhwc<<<(Bn * HWn) / 64, 256, 0, stream>>>(hu, T0);

    const int dils[3] = {2, 4, 8};
    // stage1: T0 -> T1 ; stage2: T1 -> T0 ; stage3: T0 -> d_out (NCHW)
    const float* ins[3] = {T0, T1, T0};
    float*       outsT[3] = {T1, T0, nullptr};
    const int nblk = (Bn * HWn) / 16;             // 1152

    for (int i = 0; i < 3; ++i) {
        const float* obv = (const float*)d_in[2 + 7 * i];
        const float* gv  = (const float*)d_in[4 + 7 * i];
        const float* bv  = (const float*)d_in[5 + 7 * i];
        const float* mv  = (const float*)d_in[6 + 7 * i];
        const float* vv  = (const float*)d_in[7 + 7 * i];
        const int last = (i == 2);

        fused_stage<<<nblk, 512, 0, stream>>>(
            ins[i], wb + i * Cn * KCn, owb + i * 32 * KCn, obv,
            gv, bv, mv, vv, outsT[i], last ? (float*)d_out : nullptr,
            dils[i], last);
    }
}